// Round 19
// 204.944 us; speedup vs baseline: 4.2263x; 1.0566x over previous
//
#include <hip/hip_runtime.h>
#include <hip/hip_bf16.h>

typedef __hip_bfloat16 bf16;

#define N_NODES 50000
#define N_EDGES 800000
#define NB 64

// bucketed CSR build
#define NBUCK 256
#define BUCK_R ((N_NODES + NBUCK - 1) / NBUCK)            // 196 nodes/bucket
#define BUCK_CAP 4352                                     // mean 3136, +21 sigma
#define OVF_CAP 65536
#define NBLK1 256
#define CHUNK1 ((N_EDGES + NBLK1 - 1) / NBLK1)            // 3125 edges/block
#define NIT ((CHUNK1 + 255) / 256)                        // 13 iters/thread

// k_prep block partition
#define XN_BLKS ((N_NODES + 255) / 256)                   // 196
#define PREP_BLKS (XN_BLKS + 20 + 1)

// param block offsets (floats)
#define P_W1 0
#define P_A1S 384
#define P_A1D 512
#define P_B1 640
#define P_W2 768
#define P_A2S 8960
#define P_A2D 9024
#define P_B2 9088
#define P_W3 9152
#define P_A3S 17344
#define P_A3D 17472
#define P_B3 17600
#define P_W4 17728
#define P_A4S 18112
#define P_A4D 18115
#define P_B4 18118
#define P_WC1 18121
#define P_BC1 20169
#define P_WC2 20201
#define P_BC2 20265
// factored attention vectors for conv3
#define P_W3S 20280
#define P_W3D 20344
#define P_TOTAL 20408

__device__ __forceinline__ float wave_sum(float v) {
#pragma unroll
    for (int o = 32; o >= 1; o >>= 1) v += __shfl_xor(v, o, 64);
    return v;
}
// reduction within aligned 16-lane group (xor offsets stay in-group)
__device__ __forceinline__ float g16_sum(float v) {
#pragma unroll
    for (int o = 8; o >= 1; o >>= 1) v += __shfl_xor(v, o, 64);
    return v;
}

__device__ __forceinline__ unsigned int pk2(float a, float b) {
    bf16 x = __float2bfloat16(a);
    bf16 y = __float2bfloat16(b);
    unsigned short ux = *reinterpret_cast<unsigned short*>(&x);
    unsigned short uy = *reinterpret_cast<unsigned short*>(&y);
    return ((unsigned int)uy << 16) | ux;
}
__device__ __forceinline__ float bf_lo(unsigned int u) {
    unsigned int v = u << 16;
    return *reinterpret_cast<float*>(&v);
}
__device__ __forceinline__ float bf_hi(unsigned int u) {
    unsigned int v = u & 0xffff0000u;
    return *reinterpret_cast<float*>(&v);
}

// runtime dtype helpers: flags[0]=float-inputs-are-bf16, flags[1]=ints-are-int64
__device__ __forceinline__ int ld_idx(const void* p, long long i, int is64) {
    return is64 ? (int)((const long long*)p)[i] : ((const int*)p)[i];
}
__device__ __forceinline__ float ldf(const void* p, int i, int isbf) {
    return isbf ? __bfloat162float(((const bf16*)p)[i]) : ((const float*)p)[i];
}
__device__ __forceinline__ void st_out(void* p, long long i, float v, int isbf) {
    if (isbf) ((bf16*)p)[i] = __float2bfloat16(v);
    else ((float*)p)[i] = v;
}

// unnormalized attention weight
__device__ __forceinline__ float attn_p(float esv, float edi) {
    float v = esv + edi;
    float e = (v >= 0.f) ? v : 0.2f * v;
    return __expf(fminf(e, 60.f));
}

// ---------------- fused prep (+ conv1 es/ed) ----------------
struct PTab {
    const void* src[20];
    int off[20];
    int n[20];
};

__global__ __launch_bounds__(256) void k_prep(
        const void* __restrict__ x, const void* __restrict__ eidx,
        const void* __restrict__ rW1, const void* __restrict__ rA1s,
        const void* __restrict__ rA1d, const void* __restrict__ rW3,
        const void* __restrict__ rA3s, const void* __restrict__ rA3d,
        PTab tab, float* __restrict__ pblock, float* __restrict__ x4,
        float* __restrict__ es, float* __restrict__ ed,
        int* __restrict__ gcur, int* __restrict__ ovf_cnt, int* __restrict__ flags) {
    __shared__ int scnt[2];
    __shared__ float sw[6];
    const int t = threadIdx.x;
    if (t < 2) scnt[t] = 0;
    __syncthreads();
    {
        const unsigned short* xr = (const unsigned short*)x;
        unsigned int hb = (xr[2 * t] >> 8) & 0x7F;
        if (hb >= 58 && hb <= 65) atomicAdd(&scnt[0], 1);
        if (t < 64) {
            const unsigned int* er = (const unsigned int*)eidx;
            if (er[2 * t + 1] == 0u) atomicAdd(&scnt[1], 1);
        }
    }
    __syncthreads();
    const int isbf = (scnt[0] >= 200) ? 1 : 0;
    const int is64 = (scnt[1] >= 60) ? 1 : 0;

    const int b = blockIdx.x;
    if (b < XN_BLKS) {
        if (t < 6) {
            int row = (t < 3) ? t : t - 3;
            const void* av = (t < 3) ? rA1s : rA1d;
            float s = 0.f;
            for (int k = 0; k < 128; k++)
                s = fmaf(ldf(rW1, row * 128 + k, isbf), ldf(av, k, isbf), s);
            sw[t] = s;
        }
        __syncthreads();
        int node = b * 256 + t;
        if (node < N_NODES) {
            float x0 = ldf(x, node * 3 + 0, isbf);
            float x1 = ldf(x, node * 3 + 1, isbf);
            float x2 = ldf(x, node * 3 + 2, isbf);
            float4 v = {x0, x1, x2, 0.f};
            *(float4*)&x4[node * 4] = v;
            es[node] = x0 * sw[0] + x1 * sw[1] + x2 * sw[2];
            ed[node] = x0 * sw[3] + x1 * sw[4] + x2 * sw[5];
        }
    } else if (b < XN_BLKS + 20) {
        int p = b - XN_BLKS;
        const void* s = tab.src[p];
        float* d = pblock + tab.off[p];
        int n = tab.n[p];
        for (int i = t; i < n; i += 256) d[i] = ldf(s, i, isbf);
    } else {
        if (t < NBUCK) gcur[t] = 0;
        if (t == 0) { *ovf_cnt = 0; flags[0] = isbf; flags[1] = is64; }
        if (t >= 64 && t < 128) {  // w3s/w3d: W3 [64][128] . a3s/a3d
            int k = t - 64;
            float s = 0.f, d = 0.f;
            for (int c = 0; c < 128; c++) {
                float wv = ldf(rW3, k * 128 + c, isbf);
                s = fmaf(wv, ldf(rA3s, c, isbf), s);
                d = fmaf(wv, ldf(rA3d, c, isbf), d);
            }
            pblock[P_W3S + k] = s;
            pblock[P_W3D + k] = d;
        }
    }
}

// ---------------- bucket phase ----------------
__global__ __launch_bounds__(256) void k_bucket(
        const void* __restrict__ eidx, const int* __restrict__ flags,
        int* __restrict__ gcur, unsigned int* __restrict__ stage,
        int* __restrict__ ovf_cnt, uint2* __restrict__ ovf) {
    __shared__ int hist[NBUCK];
    __shared__ int base[NBUCK];
    const int t = threadIdx.x;
    const int is64 = flags[1];
    const int e0 = blockIdx.x * CHUNK1;
    const int e1 = min(e0 + CHUNK1, N_EDGES);

    unsigned int ent[NIT];
    int bk[NIT];
    hist[t] = 0;
    __syncthreads();
#pragma unroll
    for (int it = 0; it < NIT; it++) {
        int e = e0 + t + it * 256;
        int b = -1;
        unsigned int en = 0;
        if (e < e1) {
            int r = ld_idx(eidx, (long long)N_EDGES + e, is64);
            int s = ld_idx(eidx, e, is64);
            b = r / BUCK_R;
            en = ((unsigned)(r - b * BUCK_R) << 16) | (unsigned)s;
            atomicAdd(&hist[b], 1);
        }
        ent[it] = en;
        bk[it] = b;
    }
    __syncthreads();
    int cnt = hist[t];
    base[t] = (cnt > 0) ? atomicAdd(&gcur[t], cnt) : 0;
    __syncthreads();
    hist[t] = 0;
    __syncthreads();
#pragma unroll
    for (int it = 0; it < NIT; it++) {
        int b = bk[it];
        if (b >= 0) {
            int l = atomicAdd(&hist[b], 1);
            int slot = base[b] + l;
            if (slot < BUCK_CAP) {
                stage[(size_t)b * BUCK_CAP + slot] = ent[it];
            } else {
                int oi = atomicAdd(ovf_cnt, 1);
                int r = b * BUCK_R + (int)(ent[it] >> 16);
                if (oi < OVF_CAP) ovf[oi] = make_uint2(ent[it] & 0xffffu, (unsigned)r);
            }
        }
    }
}

// ---------------- fused count+scan+fill: one block per bucket ------------------
__global__ __launch_bounds__(256) void k_fillc(
        const int* __restrict__ gcur, const unsigned int* __restrict__ stage,
        const int* __restrict__ ovf_cnt, const uint2* __restrict__ ovf,
        int* __restrict__ off, int* __restrict__ csr_send) {
    __shared__ int ovh[NBUCK];     // overflow per bucket; later per-node hist
    __shared__ int ss[NBUCK];      // scan array (bucket totals, then node counts)
    __shared__ int sstart[BUCK_R];
    __shared__ int lcur[BUCK_R];
    const int b = blockIdx.x;
    const int t = threadIdx.x;

    ovh[t] = 0;
    __syncthreads();
    const int oc = min(*ovf_cnt, OVF_CAP);
    for (int i = t; i < oc; i += 256) atomicAdd(&ovh[(int)ovf[i].y / BUCK_R], 1);
    __syncthreads();

    // bucket totals -> inclusive prefix
    int nrb = N_NODES - t * BUCK_R;
    nrb = (nrb < 0) ? 0 : ((nrb > BUCK_R) ? BUCK_R : nrb);
    int v = min(gcur[t], BUCK_CAP) + ovh[t] + nrb;
    ss[t] = v;
    __syncthreads();
#pragma unroll
    for (int o = 1; o < NBUCK; o <<= 1) {
        int add = (t >= o) ? ss[t - o] : 0;
        __syncthreads();
        ss[t] += add;
        __syncthreads();
    }
    const int total_all = ss[NBUCK - 1];
    int nrb_b = N_NODES - b * BUCK_R;
    nrb_b = (nrb_b < 0) ? 0 : ((nrb_b > BUCK_R) ? BUCK_R : nrb_b);
    const int vb = min(gcur[b], BUCK_CAP) + ovh[b] + nrb_b;
    const int bstart = ss[b] - vb;
    if (b == NBUCK - 1 && t == 0) off[N_NODES] = total_all;
    __syncthreads();

    // per-node histogram (reuse ovh)
    const int r0 = b * BUCK_R;
    const int nr = nrb_b;
    ovh[t] = 0;
    __syncthreads();
    const int cnt = min(gcur[b], BUCK_CAP);
    const unsigned int* sb = stage + (size_t)b * BUCK_CAP;
    for (int i = t; i < cnt; i += 256) atomicAdd(&ovh[sb[i] >> 16], 1);
    for (int i = t; i < oc; i += 256) {
        int r = (int)ovf[i].y;
        if (r >= r0 && r < r0 + nr) atomicAdd(&ovh[r - r0], 1);
    }
    __syncthreads();
    int vv = (t < nr) ? ovh[t] + 1 : 0;  // +1 self loop
    ss[t] = vv;
    __syncthreads();
#pragma unroll
    for (int o = 1; o < NBUCK; o <<= 1) {
        int add = (t >= o) ? ss[t - o] : 0;
        __syncthreads();
        ss[t] += add;
        __syncthreads();
    }
    if (t < nr) {
        int st = bstart + ss[t] - vv;
        sstart[t] = st;
        off[r0 + t] = st;
        lcur[t] = 1;
        csr_send[st] = r0 + t;      // self loop in slot 0
    }
    __syncthreads();
    for (int i = t; i < cnt; i += 256) {
        unsigned int e = sb[i];
        int rl = (int)(e >> 16);
        int l = atomicAdd(&lcur[rl], 1);
        csr_send[sstart[rl] + l] = (int)(e & 0xffffu);
    }
    for (int i = t; i < oc; i += 256) {
        uint2 pr = ovf[i];
        int r = (int)pr.y;
        if (r >= r0 && r < r0 + nr) {
            int rl = r - r0;
            int l = atomicAdd(&lcur[rl], 1);
            csr_send[sstart[rl] + l] = (int)pr.x;
        }
    }
}

// ---------------- conv1: 16-lane groups, gather x4 + fused post-GEMM -----------
__global__ __launch_bounds__(256) void k_wsumx3(
        const float* __restrict__ x4, const float* __restrict__ es,
        const float* __restrict__ ed, const float* __restrict__ pb,
        const int* __restrict__ off, const int* __restrict__ csr_send,
        float* __restrict__ out) {
    int node = blockIdx.x * 16 + (threadIdx.x >> 4);
    int l16 = threadIdx.x & 15;
    if (node >= N_NODES) return;
    int start = off[node], end = off[node + 1];
    float edi = ed[node];
    float a0 = 0.f, a1 = 0.f, a2 = 0.f, sl = 0.f;
    for (int j = start + l16; j < end; j += 16) {
        int s = csr_send[j];
        float p = attn_p(es[s], edi);
        sl += p;
        float4 xv = *(const float4*)&x4[s * 4];
        a0 = fmaf(p, xv.x, a0);
        a1 = fmaf(p, xv.y, a1);
        a2 = fmaf(p, xv.z, a2);
    }
    float S = g16_sum(sl);
    a0 = g16_sum(a0);
    a1 = g16_sum(a1);
    a2 = g16_sum(a2);
    float inv = 1.f / S;
    a0 *= inv; a1 *= inv; a2 *= inv;
    // fused [3]->[128] GEMM: lane computes 8 cols [8*l16, 8*l16+8)
    const float* W1 = pb + P_W1;
    const float* b1 = pb + P_B1;
    int c = l16 * 8;
    float r[8];
#pragma unroll
    for (int k = 0; k < 8; k++) {
        int cc = c + k;
        float v = fmaf(a0, W1[cc], fmaf(a1, W1[128 + cc], fmaf(a2, W1[256 + cc], b1[cc])));
        r[k] = fmaxf(v, 0.f);
    }
    float4 v0 = {r[0], r[1], r[2], r[3]};
    float4 v1 = {r[4], r[5], r[6], r[7]};
    *(float4*)&out[(size_t)node * 128 + c] = v0;
    *(float4*)&out[(size_t)node * 128 + c + 4] = v1;
}

// ---------------- register-tiled GEMM ----------------
// MODE 0: pre (es/ed + bf16 h out), used for conv2.
// MODE 3: conv3-post (bias+relu) fused with conv4-pre (128->3 + es/ed).
template <int DIN, int DINS, int DOUT, int MODE>
__global__ __launch_bounds__(256) void k_gemm(
        const float* __restrict__ in, const float* __restrict__ W,
        const float* __restrict__ as_, const float* __restrict__ ad_,
        const float* __restrict__ bias, void* __restrict__ hout,
        float* __restrict__ es, float* __restrict__ ed) {
    constexpr int KC = (DIN < 32) ? DIN : 32;
    constexpr int NCH = DIN / KC;
    constexpr int CG = DOUT / 8;
    constexpr int NT = (256 / CG) * 4;
    constexpr int NTP = NT + 4;

    __shared__ float sX[KC][NTP];
    __shared__ float sW[KC][DOUT];

    const int t = threadIdx.x;
    const int node0 = blockIdx.x * NT;
    const int nvalid = min(NT, N_NODES - node0);

    const int cg = t & (CG - 1);
    const int ng = t / CG;

    float acc[4][8] = {};

    for (int ch = 0; ch < NCH; ch++) {
        const int k0 = ch * KC;
        if (ch > 0) __syncthreads();
        for (int i = t; i < nvalid * KC; i += 256) {
            int n = i / KC, k = i - n * KC;
            sX[k][n] = in[(size_t)(node0 + n) * DINS + k0 + k];
        }
        for (int i = t; i < KC * DOUT; i += 256) {
            int k = i / DOUT, c = i - k * DOUT;
            sW[k][c] = W[(size_t)(k0 + k) * DOUT + c];
        }
        __syncthreads();

#pragma unroll 4
        for (int k = 0; k < KC; k++) {
            float4 xv = *(const float4*)&sX[k][ng * 4];
            float4 w0 = *(const float4*)&sW[k][cg * 8];
            float4 w1 = *(const float4*)&sW[k][cg * 8 + 4];
            float xs[4] = {xv.x, xv.y, xv.z, xv.w};
            float ws[8] = {w0.x, w0.y, w0.z, w0.w, w1.x, w1.y, w1.z, w1.w};
#pragma unroll
            for (int j = 0; j < 4; j++)
#pragma unroll
                for (int c = 0; c < 8; c++)
                    acc[j][c] = fmaf(xs[j], ws[c], acc[j][c]);
        }
    }

    if constexpr (MODE == 0) {
        float asv[8], adv[8];
#pragma unroll
        for (int c = 0; c < 8; c++) {
            asv[c] = as_[cg * 8 + c];
            adv[c] = ad_[cg * 8 + c];
        }
#pragma unroll
        for (int j = 0; j < 4; j++) {
            int n = ng * 4 + j;
            float e_s = 0.f, e_d = 0.f;
#pragma unroll
            for (int c = 0; c < 8; c++) {
                e_s = fmaf(acc[j][c], asv[c], e_s);
                e_d = fmaf(acc[j][c], adv[c], e_d);
            }
#pragma unroll
            for (int m = 1; m < CG; m <<= 1) {
                e_s += __shfl_xor(e_s, m, 64);
                e_d += __shfl_xor(e_d, m, 64);
            }
            if (n < nvalid) {
                if (cg == 0) {
                    es[node0 + n] = e_s;
                    ed[node0 + n] = e_d;
                }
                unsigned short* hb = (unsigned short*)hout;
                uint4 u;
                u.x = pk2(acc[j][0], acc[j][1]);
                u.y = pk2(acc[j][2], acc[j][3]);
                u.z = pk2(acc[j][4], acc[j][5]);
                u.w = pk2(acc[j][6], acc[j][7]);
                *(uint4*)&hb[(size_t)(node0 + n) * DOUT + cg * 8] = u;
            }
        }
    } else {  // MODE 3
        const float* pbase = as_;
        const float* W4 = pbase + P_W4;
        float bv[8], w40[8], w41[8], w42[8];
#pragma unroll
        for (int c = 0; c < 8; c++) {
            bv[c] = bias[cg * 8 + c];
            int row = cg * 8 + c;
            w40[c] = W4[row * 3 + 0];
            w41[c] = W4[row * 3 + 1];
            w42[c] = W4[row * 3 + 2];
        }
        float a4s0 = pbase[P_A4S], a4s1 = pbase[P_A4S + 1], a4s2 = pbase[P_A4S + 2];
        float a4d0 = pbase[P_A4D], a4d1 = pbase[P_A4D + 1], a4d2 = pbase[P_A4D + 2];
        float* h3o = (float*)hout;
#pragma unroll
        for (int j = 0; j < 4; j++) {
            int n = ng * 4 + j;
            float h40 = 0.f, h41 = 0.f, h42 = 0.f;
#pragma unroll
            for (int c = 0; c < 8; c++) {
                float v = fmaxf(acc[j][c] + bv[c], 0.f);
                h40 = fmaf(v, w40[c], h40);
                h41 = fmaf(v, w41[c], h41);
                h42 = fmaf(v, w42[c], h42);
            }
#pragma unroll
            for (int m = 1; m < CG; m <<= 1) {
                h40 += __shfl_xor(h40, m, 64);
                h41 += __shfl_xor(h41, m, 64);
                h42 += __shfl_xor(h42, m, 64);
            }
            if (n < nvalid && cg == 0) {
                es[node0 + n] = h40 * a4s0 + h41 * a4s1 + h42 * a4s2;
                ed[node0 + n] = h40 * a4d0 + h41 * a4d1 + h42 * a4d2;
                float4 vv = {h40, h41, h42, 0.f};
                *(float4*)&h3o[(size_t)(node0 + n) * 4] = vv;
            }
        }
    }
}

// ---------------- conv2: softmax+wsum, bf16 h; fused conv3 es/ed epilogue ------
__global__ __launch_bounds__(256) void k_wsum64f(
        const unsigned short* __restrict__ hb, const float* __restrict__ es,
        const float* __restrict__ ed, const float* __restrict__ pb,
        const int* __restrict__ off, const int* __restrict__ csr_send,
        float* __restrict__ out, unsigned short* __restrict__ lat16,
        float* __restrict__ es2, float* __restrict__ ed2,
        void* __restrict__ out_dev, long long out_off, const int* __restrict__ flags) {
    int wid = threadIdx.x >> 6, lane = threadIdx.x & 63;
    int node = blockIdx.x * 4 + wid;
    if (node >= N_NODES) return;
    int start = off[node], end = off[node + 1];
    float edi = ed[node];

    const int qd = lane >> 4;
    const int ql = lane & 15;
    float4 a0 = {0.f, 0.f, 0.f, 0.f}, a1 = {0.f, 0.f, 0.f, 0.f};
    float4 a2 = {0.f, 0.f, 0.f, 0.f}, a3 = {0.f, 0.f, 0.f, 0.f};
    float sl = 0.f;

    for (int base = start; base < end; base += 64) {
        int j = base + lane;
        bool valid = j < end;
        int src = valid ? csr_send[j] : 0;
        float p = valid ? attn_p(es[src], edi) : 0.f;
        sl += p;
        int cnt = min(64, end - base);
        int nq = (cnt + 3) >> 2;
        int j2 = 0;
        for (; j2 + 4 <= nq; j2 += 4) {
            int qA = 4 * j2 + qd;
            float pA = __shfl(p, qA, 64);      int sA = __shfl(src, qA, 64);
            float pB = __shfl(p, qA + 4, 64);  int sB = __shfl(src, qA + 4, 64);
            float pC = __shfl(p, qA + 8, 64);  int sC = __shfl(src, qA + 8, 64);
            float pD = __shfl(p, qA + 12, 64); int sD = __shfl(src, qA + 12, 64);
            uint2 uA = *((const uint2*)(hb + (size_t)sA * 64) + ql);
            uint2 uB = *((const uint2*)(hb + (size_t)sB * 64) + ql);
            uint2 uC = *((const uint2*)(hb + (size_t)sC * 64) + ql);
            uint2 uD = *((const uint2*)(hb + (size_t)sD * 64) + ql);
            a0.x = fmaf(pA, bf_lo(uA.x), a0.x); a0.y = fmaf(pA, bf_hi(uA.x), a0.y);
            a0.z = fmaf(pA, bf_lo(uA.y), a0.z); a0.w = fmaf(pA, bf_hi(uA.y), a0.w);
            a1.x = fmaf(pB, bf_lo(uB.x), a1.x); a1.y = fmaf(pB, bf_hi(uB.x), a1.y);
            a1.z = fmaf(pB, bf_lo(uB.y), a1.z); a1.w = fmaf(pB, bf_hi(uB.y), a1.w);
            a2.x = fmaf(pC, bf_lo(uC.x), a2.x); a2.y = fmaf(pC, bf_hi(uC.x), a2.y);
            a2.z = fmaf(pC, bf_lo(uC.y), a2.z); a2.w = fmaf(pC, bf_hi(uC.y), a2.w);
            a3.x = fmaf(pD, bf_lo(uD.x), a3.x); a3.y = fmaf(pD, bf_hi(uD.x), a3.y);
            a3.z = fmaf(pD, bf_lo(uD.y), a3.z); a3.w = fmaf(pD, bf_hi(uD.y), a3.w);
        }
        for (; j2 < nq; j2++) {
            int q = 4 * j2 + qd;
            float pq = __shfl(p, q, 64); int sq = __shfl(src, q, 64);
            uint2 u = *((const uint2*)(hb + (size_t)sq * 64) + ql);
            a0.x = fmaf(pq, bf_lo(u.x), a0.x); a0.y = fmaf(pq, bf_hi(u.x), a0.y);
            a0.z = fmaf(pq, bf_lo(u.y), a0.z); a0.w = fmaf(pq, bf_hi(u.y), a0.w);
        }
    }
    float S = wave_sum(sl);
    float inv = 1.f / S;
    float4 r;
    r.x = (a0.x + a1.x) + (a2.x + a3.x);
    r.y = (a0.y + a1.y) + (a2.y + a3.y);
    r.z = (a0.z + a1.z) + (a2.z + a3.z);
    r.w = (a0.w + a1.w) + (a2.w + a3.w);
    r.x += __shfl_xor(r.x, 16, 64); r.y += __shfl_xor(r.y, 16, 64);
    r.z += __shfl_xor(r.z, 16, 64); r.w += __shfl_xor(r.w, 16, 64);
    r.x += __shfl_xor(r.x, 32, 64); r.y += __shfl_xor(r.y, 32, 64);
    r.z += __shfl_xor(r.z, 32, 64); r.w += __shfl_xor(r.w, 32, 64);
    if (qd == 0) {
        float4 b = ((const float4*)(pb + P_B2))[ql];
        r.x = fmaf(r.x, inv, b.x); r.y = fmaf(r.y, inv, b.y);
        r.z = fmaf(r.z, inv, b.z); r.w = fmaf(r.w, inv, b.w);
        ((float4*)(out + (size_t)node * 64))[ql] = r;
        uint2 u = {pk2(r.x, r.y), pk2(r.z, r.w)};
        ((uint2*)(lat16 + (size_t)node * 64))[ql] = u;
        int isbf = flags[0];
        long long o4 = out_off + (long long)node * 64 + 4 * ql;
        st_out(out_dev, o4 + 0, r.x, isbf);
        st_out(out_dev, o4 + 1, r.y, isbf);
        st_out(out_dev, o4 + 2, r.z, isbf);
        st_out(out_dev, o4 + 3, r.w, isbf);
        const float* w3s = pb + P_W3S;
        const float* w3d = pb + P_W3D;
        float s3 = r.x * w3s[4 * ql] + r.y * w3s[4 * ql + 1] +
                   r.z * w3s[4 * ql + 2] + r.w * w3s[4 * ql + 3];
        float d3 = r.x * w3d[4 * ql] + r.y * w3d[4 * ql + 1] +
                   r.z * w3d[4 * ql + 2] + r.w * w3d[4 * ql + 3];
#pragma unroll
        for (int o = 8; o >= 1; o >>= 1) {
            s3 += __shfl_xor(s3, o, 64);
            d3 += __shfl_xor(d3, o, 64);
        }
        if (ql == 0) { es2[node] = s3; ed2[node] = d3; }
    }
}

// ---------------- conv3 aggregation: gather lat16 (64-dim bf16) ----------------
__global__ __launch_bounds__(256) void k_wsumx64(
        const unsigned short* __restrict__ lat16, const float* __restrict__ es,
        const float* __restrict__ ed, const int* __restrict__ off,
        const int* __restrict__ csr_send, float* __restrict__ lagg) {
    int wid = threadIdx.x >> 6, lane = threadIdx.x & 63;
    int node = blockIdx.x * 4 + wid;
    if (node >= N_NODES) return;
    int start = off[node], end = off[node + 1];
    float edi = ed[node];

    const int qd = lane >> 4;
    const int ql = lane & 15;
    float4 a0 = {0.f, 0.f, 0.f, 0.f}, a1 = {0.f, 0.f, 0.f, 0.f};
    float4 a2 = {0.f, 0.f, 0.f, 0.f}, a3 = {0.f, 0.f, 0.f, 0.f};
    float sl = 0.f;

    for (int base = start; base < end; base += 64) {
        int j = base + lane;
        bool valid = j < end;
        int src = valid ? csr_send[j] : 0;
        float p = valid ? attn_p(es[src], edi) : 0.f;
        sl += p;
        int cnt = min(64, end - base);
        int nq = (cnt + 3) >> 2;
        int j2 = 0;
        for (; j2 + 4 <= nq; j2 += 4) {
            int qA = 4 * j2 + qd;
            float pA = __shfl(p, qA, 64);      int sA = __shfl(src, qA, 64);
            float pB = __shfl(p, qA + 4, 64);  int sB = __shfl(src, qA + 4, 64);
            float pC = __shfl(p, qA + 8, 64);  int sC = __shfl(src, qA + 8, 64);
            float pD = __shfl(p, qA + 12, 64); int sD = __shfl(src, qA + 12, 64);
            uint2 uA = *((const uint2*)(lat16 + (size_t)sA * 64) + ql);
            uint2 uB = *((const uint2*)(lat16 + (size_t)sB * 64) + ql);
            uint2 uC = *((const uint2*)(lat16 + (size_t)sC * 64) + ql);
            uint2 uD = *((const uint2*)(lat16 + (size_t)sD * 64) + ql);
            a0.x = fmaf(pA, bf_lo(uA.x), a0.x); a0.y = fmaf(pA, bf_hi(uA.x), a0.y);
            a0.z = fmaf(pA, bf_lo(uA.y), a0.z); a0.w = fmaf(pA, bf_hi(uA.y), a0.w);
            a1.x = fmaf(pB, bf_lo(uB.x), a1.x); a1.y = fmaf(pB, bf_hi(uB.x), a1.y);
            a1.z = fmaf(pB, bf_lo(uB.y), a1.z); a1.w = fmaf(pB, bf_hi(uB.y), a1.w);
            a2.x = fmaf(pC, bf_lo(uC.x), a2.x); a2.y = fmaf(pC, bf_hi(uC.x), a2.y);
            a2.z = fmaf(pC, bf_lo(uC.y), a2.z); a2.w = fmaf(pC, bf_hi(uC.y), a2.w);
            a3.x = fmaf(pD, bf_lo(uD.x), a3.x); a3.y = fmaf(pD, bf_hi(uD.x), a3.y);
            a3.z = fmaf(pD, bf_lo(uD.y), a3.z); a3.w = fmaf(pD, bf_hi(uD.y), a3.w);
        }
        for (; j2 < nq; j2++) {
            int q = 4 * j2 + qd;
            float pq = __shfl(p, q, 64); int sq = __shfl(src, q, 64);
            uint2 u = *((const uint2*)(lat16 + (size_t)sq * 64) + ql);
            a0.x = fmaf(pq, bf_lo(u.x), a0.x); a0.y = fmaf(pq, bf_hi(u.x), a0.y);
            a0.z = fmaf(pq, bf_lo(u.y), a0.z); a0.w = fmaf(pq, bf_hi(u.y), a0.w);
        }
    }
    float S = wave_sum(sl);
    float inv = 1.f / S;
    float4 r;
    r.x = (a0.x + a1.x) + (a2.x + a3.x);
    r.y = (a0.y + a1.y) + (a2.y + a3.y);
    r.z = (a0.z + a1.z) + (a2.z + a3.z);
    r.w = (a0.w + a1.w) + (a2.w + a3.w);
    r.x += __shfl_xor(r.x, 16, 64); r.y += __shfl_xor(r.y, 16, 64);
    r.z += __shfl_xor(r.z, 16, 64); r.w += __shfl_xor(r.w, 16, 64);
    r.x += __shfl_xor(r.x, 32, 64); r.y += __shfl_xor(r.y, 32, 64);
    r.z += __shfl_xor(r.z, 32, 64); r.w += __shfl_xor(r.w, 32, 64);
    if (qd == 0) {
        r.x *= inv; r.y *= inv; r.z *= inv; r.w *= inv;
        ((float4*)(lagg + (size_t)node * 64))[ql] = r;
    }
}

// ---------------- conv4 aggregation: 16-lane groups (h3 padded f32) ------------
__global__ __launch_bounds__(256) void k_wsum3f(
        const float* __restrict__ h, const float* __restrict__ es,
        const float* __restrict__ ed, const float* __restrict__ bias,
        const int* __restrict__ off, const int* __restrict__ csr_send,
        void* __restrict__ out_dev, long long out_off, const int* __restrict__ flags) {
    int node = blockIdx.x * 16 + (threadIdx.x >> 4);
    int l16 = threadIdx.x & 15;
    if (node >= N_NODES) return;
    int start = off[node], end = off[node + 1];
    float edi = ed[node];

    float a0 = 0.f, a1 = 0.f, a2 = 0.f, sl = 0.f;
    for (int j = start + l16; j < end; j += 16) {
        int s = csr_send[j];
        float p = attn_p(es[s], edi);
        sl += p;
        float4 rv = *(const float4*)(h + (size_t)s * 4);
        a0 = fmaf(p, rv.x, a0);
        a1 = fmaf(p, rv.y, a1);
        a2 = fmaf(p, rv.z, a2);
    }
    float S = g16_sum(sl);
    a0 = g16_sum(a0);
    a1 = g16_sum(a1);
    a2 = g16_sum(a2);
    if (l16 < 3) {
        float inv = 1.f / S;
        float v = fmaf((l16 == 0 ? a0 : (l16 == 1 ? a1 : a2)), inv, bias[l16]);
        st_out(out_dev, out_off + (long long)node * 3 + l16, v, flags[0]);
    }
}

// ---------------- pooling + classifier (fused) ----------------
#define POOL_W 16
__global__ void k_poolcls(const float* __restrict__ latent, const void* __restrict__ batch,
                          const int* __restrict__ flags, const float* __restrict__ pb,
                          void* __restrict__ out_dev, long long out_off) {
    int b = blockIdx.x;
    int lane = threadIdx.x & 63;
    int wave = threadIdx.x >> 6;
    int is64 = flags[1];
    int lo = 0, hi = N_NODES;
    while (lo < hi) { int mid = (lo + hi) >> 1; if (ld_idx(batch, mid, is64) < b) lo = mid + 1; else hi = mid; }
    int start = lo;
    lo = 0; hi = N_NODES;
    while (lo < hi) { int mid = (lo + hi) >> 1; if (ld_idx(batch, mid, is64) < b + 1) lo = mid + 1; else hi = mid; }
    int end = lo;
    float s = 0.f;
    for (int n = start + wave; n < end; n += POOL_W) s += latent[(size_t)n * 64 + lane];
    __shared__ float red[POOL_W][64];
    __shared__ float ps[64];
    red[wave][lane] = s;
    __syncthreads();
    if (wave == 0) {
        float t = s;
#pragma unroll
        for (int w2 = 1; w2 < POOL_W; w2++) t += red[w2][lane];
        float cnt = (float)(end - start);
        ps[lane] = t / fmaxf(cnt, 1.f);
    }
    __syncthreads();
    if (wave == 0 && lane < 32) {
        float z = pb[P_BC1 + lane];
        for (int c = 0; c < 64; c++) z = fmaf(ps[c], pb[P_WC1 + c * 32 + lane], z);
        z = fmaxf(z, 0.f);
        float p0 = z * pb[P_WC2 + lane * 2];
        float p1 = z * pb[P_WC2 + lane * 2 + 1];
#pragma unroll
        for (int o = 16; o >= 1; o >>= 1) {
            p0 += __shfl_xor(p0, o, 64);
            p1 += __shfl_xor(p1, o, 64);
        }
        if (lane == 0) {
            int isbf = flags[0];
            st_out(out_dev, out_off + b * 2 + 0, p0 + pb[P_BC2], isbf);
            st_out(out_dev, out_off + b * 2 + 1, p1 + pb[P_BC2 + 1], isbf);
        }
    }
}

extern "C" void kernel_launch(void* const* d_in, const int* in_sizes, int n_in,
                              void* d_out, int out_size, void* d_ws, size_t ws_size,
                              hipStream_t stream) {
    const void* x    = d_in[0];
    const void* eidx = d_in[1];
    const void* batch= d_in[2];

    // workspace carve-up (256B aligned)
    char* w = (char*)d_ws;
    size_t o = 0;
    auto carve = [&](size_t bytes) { void* p = w + o; o = (o + bytes + 255) & ~(size_t)255; return p; };
    int* flags    = (int*)carve(8 * sizeof(int));
    int* off      = (int*)carve((N_NODES + 1) * sizeof(int));
    int* gcur     = (int*)carve(NBUCK * sizeof(int));
    int* ovf_cnt  = (int*)carve(sizeof(int));
    int* csr_send = (int*)carve((size_t)(N_EDGES + N_NODES) * sizeof(int));
    unsigned int* stage = (unsigned int*)carve((size_t)NBUCK * BUCK_CAP * sizeof(unsigned int));
    uint2* ovf    = (uint2*)carve((size_t)OVF_CAP * sizeof(uint2));
    float* pblock = (float*)carve(P_TOTAL * sizeof(float));
    float* x4     = (float*)carve((size_t)N_NODES * 4 * sizeof(float));
    float* buf0   = (float*)carve((size_t)N_NODES * 128 * sizeof(float));
    unsigned short* hb = (unsigned short*)carve((size_t)N_NODES * 64 * sizeof(unsigned short));
    unsigned short* lat16 = (unsigned short*)carve((size_t)N_NODES * 64 * sizeof(unsigned short));
    float* lagg   = (float*)carve((size_t)N_NODES * 64 * sizeof(float));
    float* h3     = (float*)carve((size_t)N_NODES * 4 * sizeof(float));
    float* es     = (float*)carve(N_NODES * sizeof(float));
    float* ed     = (float*)carve(N_NODES * sizeof(float));
    float* es2    = (float*)carve(N_NODES * sizeof(float));
    float* ed2    = (float*)carve(N_NODES * sizeof(float));

    int gW = N_NODES / 4;
    int g16 = (N_NODES + 15) / 16;

    // fused prep (+conv1 es/ed)
    PTab tab;
    const int pn[20]  = {384,128,128,128, 8192,64,64,64, 8192,128,128,128, 384,3,3,3, 2048,32,64,2};
    const int pof[20] = {P_W1,P_A1S,P_A1D,P_B1, P_W2,P_A2S,P_A2D,P_B2, P_W3,P_A3S,P_A3D,P_B3,
                         P_W4,P_A4S,P_A4D,P_B4, P_WC1,P_BC1,P_WC2,P_BC2};
    for (int i = 0; i < 20; i++) { tab.src[i] = d_in[3 + i]; tab.off[i] = pof[i]; tab.n[i] = pn[i]; }
    k_prep<<<PREP_BLKS, 256, 0, stream>>>(x, eidx, d_in[3], d_in[4], d_in[5],
                                          d_in[11], d_in[12], d_in[13],
                                          tab, pblock, x4, es, ed, gcur, ovf_cnt, flags);

    // CSR build (2 kernels)
    k_bucket<<<NBLK1, 256, 0, stream>>>(eidx, flags, gcur, stage, ovf_cnt, ovf);
    k_fillc<<<NBUCK, 256, 0, stream>>>(gcur, stage, ovf_cnt, ovf, off, csr_send);

    const long long OFF_RECON = 0, OFF_LATENT = 150000, OFF_NOISE = 3350000;

    int g128 = (N_NODES + 127) / 128;
    int g64  = (N_NODES + 63) / 64;

    // conv1: gather x (16-lane groups) + fused post-GEMM -> buf0
    k_wsumx3<<<g16, 256, 0, stream>>>(x4, es, ed, pblock, off, csr_send, buf0);

    // conv2: GEMM -> bf16 h + es/ed; gather -> latent (+ fused conv3 es2/ed2)
    k_gemm<128, 128, 64, 0><<<g128, 256, 0, stream>>>(buf0, pblock + P_W2, pblock + P_A2S,
                                                      pblock + P_A2D, pblock, hb, es, ed);
    k_wsum64f<<<gW, 256, 0, stream>>>(hb, es, ed, pblock, off, csr_send,
                                      buf0, lat16, es2, ed2, d_out, OFF_LATENT, flags);

    // pooling + classifier
    k_poolcls<<<NB, POOL_W * 64, 0, stream>>>(buf0, batch, flags, pblock, d_out, OFF_NOISE);

    // conv3 gather -> lagg; fused conv3-post+conv4-pre GEMM -> h3 + es/ed
    k_wsumx64<<<gW, 256, 0, stream>>>(lat16, es2, ed2, off, csr_send, lagg);
    k_gemm<64, 64, 128, 3><<<g64, 256, 0, stream>>>(lagg, pblock + P_W3, pblock, pblock,
                                                    pblock + P_B3, h3, es, ed);

    // conv4 gather (16-lane groups) -> reconstructed
    k_wsum3f<<<g16, 256, 0, stream>>>(h3, es, ed, pblock + P_B4, off, csr_send,
                                      d_out, OFF_RECON, flags);
}